// Round 20
// baseline (111.038 us; speedup 1.0000x reference)
//
#include <hip/hip_runtime.h>

// ---------------- problem constants (fixed by reference) ----------------
#define T_DIM 110
#define B_DIM 256
#define D_DIM 512
#define H_DIM 512
#define K_CAT 1024              // K layout: interleaved (fr0,fi0,fr1,fi1,...)
#define M_DIM (T_DIM * B_DIM)   // 28160
#define BD    (B_DIM * D_DIM)   // 131072

typedef float f32x4 __attribute__((ext_vector_type(4)));
typedef short bf16x8 __attribute__((ext_vector_type(8)));

static __device__ __forceinline__ unsigned short f2bf(float f) {
    unsigned u = __builtin_bit_cast(unsigned, f);
    u += 0x7fffu + ((u >> 16) & 1u);      // round-to-nearest-even
    return (unsigned short)(u >> 16);
}

// ---------------- kernel 1: small prep (turn table + bias only) ---------------
// Bt prep is folded into the scan kernel (its idle latency cycles absorb it).
__global__ __launch_bounds__(256) void prep_tt_kernel(
    const float* __restrict__ b1,
    const float* __restrict__ turna, const float* __restrict__ turnb,
    float* __restrict__ bias2,         // [H]
    float4* __restrict__ TT)           // [T][D]
{
    int i = blockIdx.x * 256 + threadIdx.x;
    if (i < H_DIM) bias2[i] = 2.0f * b1[i];
    if (i < T_DIM * D_DIM) {
        float s1, c1, s2, c2;
        __sincosf(turna[i], &s1, &c1);
        __sincosf(turnb[i], &s2, &c2);
        TT[i] = make_float4(c1, s1, c2, s2);
    }
}

// ---------------- kernel 2: fused features + scan (+ Bt prep preamble) --------
// Scan loop body byte-identical to R19 (measured 72-74 us, absmax 0.03125).
// PREAMBLE: this kernel's 512 blocks also convert Bt (524288 bf16 elems, 4 per
// thread) — the scan is latency-bound (VALUBusy 27%), so this work hides in
// its idle cycles and the separate prep launch shrinks to TT+bias (~1.5 us).
// Bt[h][2j]=(W1+W2)[h][j]; Bt[h][2j+1]=(W1-W2)[h][j].
__global__ __launch_bounds__(256, 1) void feat_scan_kernel(
    const float* __restrict__ a, const float* __restrict__ v,
    const float* __restrict__ l, const float* __restrict__ qmask,
    const float* __restrict__ mu_a, const float* __restrict__ mu_v,
    const float* __restrict__ mu_l,
    const float* __restrict__ shifta, const float* __restrict__ shiftv,
    const float4* __restrict__ TT,
    const float* __restrict__ W1, const float* __restrict__ W2,
    unsigned short* __restrict__ Bt,   // [H][K_CAT] bf16
    unsigned int* __restrict__ A32)    // [M][K_CAT/2] dwords (fr|fi<<16)
{
    __shared__ float qm_s[T_DIM], mua_s[T_DIM], muv_s[T_DIM], mul_s[T_DIM];
    const int tx = threadIdx.x;
    const int b  = blockIdx.x >> 1;
    const int d  = ((blockIdx.x & 1) << 8) + tx;

    // ---- Bt preamble: 4 consecutive Bt elements per thread ----
    {
        const int tid = blockIdx.x * 256 + tx;       // 0 .. 131071
        const int h   = tid >> 8;                    // 0 .. 511
        const int m   = tid & 255;                   // j0 = 2m
        const float2 w1 = *reinterpret_cast<const float2*>(W1 + (size_t)h * D_DIM + 2 * m);
        const float2 w2 = *reinterpret_cast<const float2*>(W2 + (size_t)h * D_DIM + 2 * m);
        ushort4 o;
        o.x = f2bf(w1.x + w2.x);
        o.y = f2bf(w1.x - w2.x);
        o.z = f2bf(w1.y + w2.y);
        o.w = f2bf(w1.y - w2.y);
        *reinterpret_cast<ushort4*>(Bt + (size_t)tid * 4) = o;
    }

    if (tx < T_DIM) {
        qm_s[tx]  = qmask[(size_t)(tx * B_DIM + b) * 2];
        mua_s[tx] = mu_a[tx];
        muv_s[tx] = mu_v[tx];
        mul_s[tx] = mu_l[tx];
    }
    const float sa = shifta[d];
    const float sv = shiftv[d];
    __syncthreads();

    const size_t gbase = (size_t)b * D_DIM + d;

    // ---- prologue: fill the 4 slots (t = 0..3) ----
    float  s0a = a[gbase],                 s0v = v[gbase],
           s0l = l[gbase];
    float4 s0t = TT[d];
    float  s1a = a[(size_t)1 * BD + gbase], s1v = v[(size_t)1 * BD + gbase],
           s1l = l[(size_t)1 * BD + gbase];
    float4 s1t = TT[1 * D_DIM + d];
    float  s2a = a[(size_t)2 * BD + gbase], s2v = v[(size_t)2 * BD + gbase],
           s2l = l[(size_t)2 * BD + gbase];
    float4 s2t = TT[2 * D_DIM + d];
    float  s3a = a[(size_t)3 * BD + gbase], s3v = v[(size_t)3 * BD + gbase],
           s3l = l[(size_t)3 * BD + gbase];
    float4 s3t = TT[3 * D_DIM + d];

    // pre-init (1,1): with gate=0 at t=0 the generic select reproduces the
    // reference's t=0 rule exactly.
    float pAr = 1.f, pAi = 1.f, pBr = 1.f, pBi = 1.f;

#define ITER(tt_, SA_, SV_, SL_, ST_)                                          \
    {                                                                          \
        const int t_ = (tt_);                                                  \
        const float qa = qm_s[t_], ma = mua_s[t_],                             \
                    mv = muv_s[t_], ml = mul_s[t_];                            \
        float sA, cA, sV, cV, sL, cL;                                          \
        __sincosf(SA_ + sa, &sA, &cA);                                         \
        __sincosf(SV_ + sv, &sV, &cV);                                         \
        __sincosf(SL_,      &sL, &cL);                                         \
        float fr = ml * cL + ma * cA + mv * cV;                                \
        float fi = ml * sL + ma * sA + mv * sV;                                \
        const bool isA = qa > 0.5f;                                            \
        const float cp = isA ? ST_.x : ST_.z;                                  \
        const float sp = isA ? ST_.y : ST_.w;                                  \
        const float pr = isA ? pAr : pBr;                                      \
        const float pi = isA ? pAi : pBi;                                      \
        const float tr = pr * cp - pi * sp;                                    \
        const float ti = pr * sp + pi * cp;                                    \
        const float gate = (t_ == 0) ? 0.0f : 1.0f;                            \
        const float m2 = fmaxf(tr * tr + ti * ti, 1e-30f);                     \
        const float inv = gate * __builtin_amdgcn_rsqf(m2);                    \
        fr += tr * inv;                                                        \
        fi += ti * inv;                                                        \
        pAr = isA ? fr : pAr;  pAi = isA ? fi : pAi;                           \
        pBr = isA ? pBr : fr;  pBi = isA ? pBi : fi;                           \
        A32[(size_t)(t_ * B_DIM + b) * (K_CAT / 2) + d] =                      \
            (unsigned)f2bf(fr) | ((unsigned)f2bf(fi) << 16);                   \
        /* reload SAME slot for t+4 (clamped; tail dups harmless) */           \
        const int tnx = (t_ + 4 < T_DIM) ? t_ + 4 : T_DIM - 1;                 \
        SA_ = a[(size_t)tnx * BD + gbase];                                     \
        SV_ = v[(size_t)tnx * BD + gbase];                                     \
        SL_ = l[(size_t)tnx * BD + gbase];                                     \
        ST_ = TT[(size_t)tnx * D_DIM + d];                                     \
        /* directional fence: VMEM may not cross; VALU/SALU/DS may */          \
        __builtin_amdgcn_sched_barrier(0x387);                                 \
    }

    // 27 groups cover t = 0..107; peel 108 (slot0), 109 (slot1).
    for (int tb = 0; tb < 108; tb += 4) {
        ITER(tb,     s0a, s0v, s0l, s0t)
        ITER(tb + 1, s1a, s1v, s1l, s1t)
        ITER(tb + 2, s2a, s2v, s2l, s2t)
        ITER(tb + 3, s3a, s3v, s3l, s3t)
    }
    ITER(108, s0a, s0v, s0l, s0t)
    ITER(109, s1a, s1v, s1l, s1t)
#undef ITER
}

// ---------------- kernel 3: bf16 MFMA GEMM  C = A @ Bt^T + bias ---------------
// (R19 version, byte-identical.) m97 1-phase structure, grid axes swapped:
// blockIdx.x = N-tile (4, fast) so A-tile sharers are dispatch-adjacent (L2).
// 128x128 tile, BK=64, global_load_lds width-16 into linear LDS (32 KB),
// 4 waves (2x2), 4x4 frags of 16x16x32.
#define BM 128
#define BN 128
#define BK 64

__global__ __launch_bounds__(256) void gemm_kernel(
    const unsigned short* __restrict__ A,
    const unsigned short* __restrict__ Bt,
    const float* __restrict__ bias2,
    float* __restrict__ C)
{
    __shared__ __align__(16) unsigned short As[BM * BK];   // 16 KB, linear
    __shared__ __align__(16) unsigned short Bs[BN * BK];   // 16 KB, linear

    const int tid = threadIdx.x;
    const int wave = tid >> 6;
    const int lane = tid & 63;
    const int wr = wave >> 1;          // 0..1 (M dir)
    const int wc = wave & 1;           // 0..1 (N dir)
    const int m0 = blockIdx.y * BM;    // y = M-tile (220)
    const int n0 = blockIdx.x * BN;    // x = N-tile (4, fast)
    const int lrow = lane & 15;
    const int lk8 = (lane >> 4) * 8;   // k-offset of this lane's 8 elements

    const int srow = wave * 32;        // first row this wave stages
    const int lrow8 = lane >> 3;       // row within 8-row group
    const int lchunk = lane & 7;       // 16B chunk within row

    f32x4 acc[4][4] = {};

    for (int k0 = 0; k0 < K_CAT; k0 += BK) {
        #pragma unroll
        for (int c = 0; c < 4; ++c) {
            const int row = srow + c * 8 + lrow8;
            {
                const unsigned short* gp = A + (size_t)(m0 + row) * K_CAT + k0 + lchunk * 8;
                unsigned short* lp = As + (srow + c * 8) * BK + lane * 8;
                __builtin_amdgcn_global_load_lds(
                    (const __attribute__((address_space(1))) unsigned int*)gp,
                    (__attribute__((address_space(3))) unsigned int*)lp,
                    16, 0, 0);
            }
            {
                const unsigned short* gp = Bt + (size_t)(n0 + row) * K_CAT + k0 + lchunk * 8;
                unsigned short* lp = Bs + (srow + c * 8) * BK + lane * 8;
                __builtin_amdgcn_global_load_lds(
                    (const __attribute__((address_space(1))) unsigned int*)gp,
                    (__attribute__((address_space(3))) unsigned int*)lp,
                    16, 0, 0);
            }
        }
        __syncthreads();

        bf16x8 af[4][2], bfv[4][2];
        #pragma unroll
        for (int m = 0; m < 4; ++m)
            #pragma unroll
            for (int kk = 0; kk < 2; ++kk)
                af[m][kk] = *reinterpret_cast<const bf16x8*>(
                    &As[(wr * 64 + m * 16 + lrow) * BK + kk * 32 + lk8]);
        #pragma unroll
        for (int n = 0; n < 4; ++n)
            #pragma unroll
            for (int kk = 0; kk < 2; ++kk)
                bfv[n][kk] = *reinterpret_cast<const bf16x8*>(
                    &Bs[(wc * 64 + n * 16 + lrow) * BK + kk * 32 + lk8]);

        #pragma unroll
        for (int kk = 0; kk < 2; ++kk)
            #pragma unroll
            for (int m = 0; m < 4; ++m)
                #pragma unroll
                for (int n = 0; n < 4; ++n)
                    acc[m][n] = __builtin_amdgcn_mfma_f32_16x16x32_bf16(
                        af[m][kk], bfv[n][kk], acc[m][n], 0, 0, 0);
        __syncthreads();
    }

    // -------- epilogue: C/D layout col=lane&15, row=(lane>>4)*4+r  (m89/m91)
    const int rbase = m0 + wr * 64 + (lane >> 4) * 4;
    const int cbase = n0 + wc * 64;
    #pragma unroll
    for (int n = 0; n < 4; ++n) {
        const int col = cbase + n * 16 + lrow;
        const float bv = bias2[col];
        #pragma unroll
        for (int m = 0; m < 4; ++m) {
            const int row0 = rbase + m * 16;
            #pragma unroll
            for (int r = 0; r < 4; ++r) {
                C[(size_t)(row0 + r) * H_DIM + col] = acc[m][n][r] + bv;
            }
        }
    }
}

// ---------------- launcher ----------------
extern "C" void kernel_launch(void* const* d_in, const int* in_sizes, int n_in,
                              void* d_out, int out_size, void* d_ws, size_t ws_size,
                              hipStream_t stream) {
    const float* a      = (const float*)d_in[0];
    const float* v      = (const float*)d_in[1];
    const float* l      = (const float*)d_in[2];
    const float* qmask  = (const float*)d_in[3];
    // d_in[4] umask: unused by reference
    const float* mu_a   = (const float*)d_in[5];
    const float* mu_v   = (const float*)d_in[6];
    const float* mu_l   = (const float*)d_in[7];
    const float* shifta = (const float*)d_in[8];
    const float* shiftv = (const float*)d_in[9];
    const float* turna  = (const float*)d_in[10];
    const float* turnb  = (const float*)d_in[11];
    const float* W1     = (const float*)d_in[12];
    const float* b1     = (const float*)d_in[13];
    const float* W2     = (const float*)d_in[14];
    // d_in[15] b2: cancels in xr+xi
    float* out = (float*)d_out;

    char* ws = (char*)d_ws;
    unsigned short* Afeat = (unsigned short*)ws;                       // M*K_CAT bf16
    size_t offB  = (size_t)M_DIM * K_CAT * sizeof(unsigned short);     // 57.7 MB
    unsigned short* Bt = (unsigned short*)(ws + offB);                 // H*K_CAT bf16
    size_t offBias = offB + (size_t)H_DIM * K_CAT * sizeof(unsigned short);
    float* bias2 = (float*)(ws + offBias);
    size_t offTT = offBias + 4096;
    float4* TT = (float4*)(ws + offTT);                                // T*D float4

    prep_tt_kernel<<<(T_DIM * D_DIM + 255) / 256, 256, 0, stream>>>(
        b1, turna, turnb, bias2, TT);
    feat_scan_kernel<<<B_DIM * 2, 256, 0, stream>>>(
        a, v, l, qmask, mu_a, mu_v, mu_l, shifta, shiftv, TT,
        W1, W2, Bt, (unsigned int*)Afeat);
    dim3 grid(H_DIM / BN, M_DIM / BM);     // x = N-tiles (4, fast), y = M-tiles
    gemm_kernel<<<grid, 256, 0, stream>>>(Afeat, Bt, bias2, out);
}

// Round 21
// 109.631 us; speedup vs baseline: 1.0128x; 1.0128x over previous
//
#include <hip/hip_runtime.h>

// ---------------- problem constants (fixed by reference) ----------------
#define T_DIM 110
#define B_DIM 256
#define D_DIM 512
#define H_DIM 512
#define K_CAT 1024              // K layout: interleaved (fr0,fi0,fr1,fi1,...)
#define M_DIM (T_DIM * B_DIM)   // 28160
#define BD    (B_DIM * D_DIM)   // 131072

typedef float f32x4 __attribute__((ext_vector_type(4)));
typedef short bf16x8 __attribute__((ext_vector_type(8)));

static __device__ __forceinline__ unsigned short f2bf(float f) {
    unsigned u = __builtin_bit_cast(unsigned, f);
    u += 0x7fffu + ((u >> 16) & 1u);      // round-to-nearest-even
    return (unsigned short)(u >> 16);
}

// ---------------- kernel 1: fused prep (weights + bias + turn table) ----------
// Bt[h][2j] = (W1+W2)[h][j]; Bt[h][2j+1] = (W1-W2)[h][j]; bias = 2*b1
// (b2 cancels in xr+xi). TT[t][d] = (cos ta, sin ta, cos tb, sin tb).
__global__ __launch_bounds__(256) void prep_all_kernel(
    const float* __restrict__ W1, const float* __restrict__ b1,
    const float* __restrict__ W2,
    const float* __restrict__ turna, const float* __restrict__ turnb,
    unsigned short* __restrict__ Bt,   // [H][K_CAT] bf16
    float* __restrict__ bias2,         // [H]
    float4* __restrict__ TT)           // [T][D]
{
    int i = blockIdx.x * 256 + threadIdx.x;
    if (i < H_DIM) bias2[i] = 2.0f * b1[i];
    if (i < T_DIM * D_DIM) {
        float s1, c1, s2, c2;
        __sincosf(turna[i], &s1, &c1);
        __sincosf(turnb[i], &s2, &c2);
        TT[i] = make_float4(c1, s1, c2, s2);
    }
    if (i < H_DIM * K_CAT) {
        int h = i / K_CAT;
        int k = i % K_CAT;
        int j = k >> 1;
        float w = (k & 1) ? (W1[h * D_DIM + j] - W2[h * D_DIM + j])
                          : (W1[h * D_DIM + j] + W2[h * D_DIM + j]);
        Bt[i] = f2bf(w);
    }
}

// ---------------- kernel 2: fused features + scan -> A[M][K_CAT] bf16 ----------
// (R13/R19 version, byte-identical — 72-74 us, absmax 0.03125. 13 structurally
// distinct latency-hiding attempts documented across R2-R18 all land at
// 72-104 us: compiler waitcnt/sinking policy caps in-flight depth at HIP
// source; grid is structurally limited to 2 waves/SIMD by the serial-in-T
// recurrence.) Slot-static register ring depth 4, unroll 4; sched_barrier
// (0x387) blocks only VMEM from crossing iteration boundaries;
// rsq(max(m2,1e-30)) replaces the IEEE divide (turn==0 stays exact).
__global__ __launch_bounds__(256, 1) void feat_scan_kernel(
    const float* __restrict__ a, const float* __restrict__ v,
    const float* __restrict__ l, const float* __restrict__ qmask,
    const float* __restrict__ mu_a, const float* __restrict__ mu_v,
    const float* __restrict__ mu_l,
    const float* __restrict__ shifta, const float* __restrict__ shiftv,
    const float4* __restrict__ TT,
    unsigned int* __restrict__ A32)    // [M][K_CAT/2] dwords (fr|fi<<16)
{
    __shared__ float qm_s[T_DIM], mua_s[T_DIM], muv_s[T_DIM], mul_s[T_DIM];
    const int tx = threadIdx.x;
    const int b  = blockIdx.x >> 1;
    const int d  = ((blockIdx.x & 1) << 8) + tx;
    if (tx < T_DIM) {
        qm_s[tx]  = qmask[(size_t)(tx * B_DIM + b) * 2];
        mua_s[tx] = mu_a[tx];
        muv_s[tx] = mu_v[tx];
        mul_s[tx] = mu_l[tx];
    }
    const float sa = shifta[d];
    const float sv = shiftv[d];
    __syncthreads();

    const size_t gbase = (size_t)b * D_DIM + d;

    // ---- prologue: fill the 4 slots (t = 0..3) ----
    float  s0a = a[gbase],                 s0v = v[gbase],
           s0l = l[gbase];
    float4 s0t = TT[d];
    float  s1a = a[(size_t)1 * BD + gbase], s1v = v[(size_t)1 * BD + gbase],
           s1l = l[(size_t)1 * BD + gbase];
    float4 s1t = TT[1 * D_DIM + d];
    float  s2a = a[(size_t)2 * BD + gbase], s2v = v[(size_t)2 * BD + gbase],
           s2l = l[(size_t)2 * BD + gbase];
    float4 s2t = TT[2 * D_DIM + d];
    float  s3a = a[(size_t)3 * BD + gbase], s3v = v[(size_t)3 * BD + gbase],
           s3l = l[(size_t)3 * BD + gbase];
    float4 s3t = TT[3 * D_DIM + d];

    // pre-init (1,1): with gate=0 at t=0 the generic select reproduces the
    // reference's t=0 rule exactly.
    float pAr = 1.f, pAi = 1.f, pBr = 1.f, pBi = 1.f;

#define ITER(tt_, SA_, SV_, SL_, ST_)                                          \
    {                                                                          \
        const int t_ = (tt_);                                                  \
        const float qa = qm_s[t_], ma = mua_s[t_],                             \
                    mv = muv_s[t_], ml = mul_s[t_];                            \
        float sA, cA, sV, cV, sL, cL;                                          \
        __sincosf(SA_ + sa, &sA, &cA);                                         \
        __sincosf(SV_ + sv, &sV, &cV);                                         \
        __sincosf(SL_,      &sL, &cL);                                         \
        float fr = ml * cL + ma * cA + mv * cV;                                \
        float fi = ml * sL + ma * sA + mv * sV;                                \
        const bool isA = qa > 0.5f;                                            \
        const float cp = isA ? ST_.x : ST_.z;                                  \
        const float sp = isA ? ST_.y : ST_.w;                                  \
        const float pr = isA ? pAr : pBr;                                      \
        const float pi = isA ? pAi : pBi;                                      \
        const float tr = pr * cp - pi * sp;                                    \
        const float ti = pr * sp + pi * cp;                                    \
        const float gate = (t_ == 0) ? 0.0f : 1.0f;                            \
        const float m2 = fmaxf(tr * tr + ti * ti, 1e-30f);                     \
        const float inv = gate * __builtin_amdgcn_rsqf(m2);                    \
        fr += tr * inv;                                                        \
        fi += ti * inv;                                                        \
        pAr = isA ? fr : pAr;  pAi = isA ? fi : pAi;                           \
        pBr = isA ? pBr : fr;  pBi = isA ? pBi : fi;                           \
        A32[(size_t)(t_ * B_DIM + b) * (K_CAT / 2) + d] =                      \
            (unsigned)f2bf(fr) | ((unsigned)f2bf(fi) << 16);                   \
        /* reload SAME slot for t+4 (clamped; tail dups harmless) */           \
        const int tnx = (t_ + 4 < T_DIM) ? t_ + 4 : T_DIM - 1;                 \
        SA_ = a[(size_t)tnx * BD + gbase];                                     \
        SV_ = v[(size_t)tnx * BD + gbase];                                     \
        SL_ = l[(size_t)tnx * BD + gbase];                                     \
        ST_ = TT[(size_t)tnx * D_DIM + d];                                     \
        /* directional fence: VMEM may not cross; VALU/SALU/DS may */          \
        __builtin_amdgcn_sched_barrier(0x387);                                 \
    }

    // 27 groups cover t = 0..107; peel 108 (slot0), 109 (slot1).
    for (int tb = 0; tb < 108; tb += 4) {
        ITER(tb,     s0a, s0v, s0l, s0t)
        ITER(tb + 1, s1a, s1v, s1l, s1t)
        ITER(tb + 2, s2a, s2v, s2l, s2t)
        ITER(tb + 3, s3a, s3v, s3l, s3t)
    }
    ITER(108, s0a, s0v, s0l, s0t)
    ITER(109, s1a, s1v, s1l, s1t)
#undef ITER
}

// ---------------- kernel 3: bf16 MFMA GEMM  C = A @ Bt^T + bias ---------------
// m97 1-phase structure, grid axes swapped: blockIdx.x = N-tile (4, fast) so
// the 4 blocks sharing one A-tile are dispatch-adjacent -> A-tile L2-resident
// (R19 measured -2 us vs M-fast order; GEMM is HBM-bound at ~5.6 TB/s ~ 88%
// of achievable). 128x128 tile, BK=64, global_load_lds width-16 into linear
// LDS (32 KB), 4 waves (2x2), 4x4 frags of 16x16x32.
#define BM 128
#define BN 128
#define BK 64

__global__ __launch_bounds__(256) void gemm_kernel(
    const unsigned short* __restrict__ A,
    const unsigned short* __restrict__ Bt,
    const float* __restrict__ bias2,
    float* __restrict__ C)
{
    __shared__ __align__(16) unsigned short As[BM * BK];   // 16 KB, linear
    __shared__ __align__(16) unsigned short Bs[BN * BK];   // 16 KB, linear

    const int tid = threadIdx.x;
    const int wave = tid >> 6;
    const int lane = tid & 63;
    const int wr = wave >> 1;          // 0..1 (M dir)
    const int wc = wave & 1;           // 0..1 (N dir)
    const int m0 = blockIdx.y * BM;    // y = M-tile (220)
    const int n0 = blockIdx.x * BN;    // x = N-tile (4, fast)
    const int lrow = lane & 15;
    const int lk8 = (lane >> 4) * 8;   // k-offset of this lane's 8 elements

    const int srow = wave * 32;        // first row this wave stages
    const int lrow8 = lane >> 3;       // row within 8-row group
    const int lchunk = lane & 7;       // 16B chunk within row

    f32x4 acc[4][4] = {};

    for (int k0 = 0; k0 < K_CAT; k0 += BK) {
        #pragma unroll
        for (int c = 0; c < 4; ++c) {
            const int row = srow + c * 8 + lrow8;
            {
                const unsigned short* gp = A + (size_t)(m0 + row) * K_CAT + k0 + lchunk * 8;
                unsigned short* lp = As + (srow + c * 8) * BK + lane * 8;
                __builtin_amdgcn_global_load_lds(
                    (const __attribute__((address_space(1))) unsigned int*)gp,
                    (__attribute__((address_space(3))) unsigned int*)lp,
                    16, 0, 0);
            }
            {
                const unsigned short* gp = Bt + (size_t)(n0 + row) * K_CAT + k0 + lchunk * 8;
                unsigned short* lp = Bs + (srow + c * 8) * BK + lane * 8;
                __builtin_amdgcn_global_load_lds(
                    (const __attribute__((address_space(1))) unsigned int*)gp,
                    (__attribute__((address_space(3))) unsigned int*)lp,
                    16, 0, 0);
            }
        }
        __syncthreads();

        bf16x8 af[4][2], bfv[4][2];
        #pragma unroll
        for (int m = 0; m < 4; ++m)
            #pragma unroll
            for (int kk = 0; kk < 2; ++kk)
                af[m][kk] = *reinterpret_cast<const bf16x8*>(
                    &As[(wr * 64 + m * 16 + lrow) * BK + kk * 32 + lk8]);
        #pragma unroll
        for (int n = 0; n < 4; ++n)
            #pragma unroll
            for (int kk = 0; kk < 2; ++kk)
                bfv[n][kk] = *reinterpret_cast<const bf16x8*>(
                    &Bs[(wc * 64 + n * 16 + lrow) * BK + kk * 32 + lk8]);

        #pragma unroll
        for (int kk = 0; kk < 2; ++kk)
            #pragma unroll
            for (int m = 0; m < 4; ++m)
                #pragma unroll
                for (int n = 0; n < 4; ++n)
                    acc[m][n] = __builtin_amdgcn_mfma_f32_16x16x32_bf16(
                        af[m][kk], bfv[n][kk], acc[m][n], 0, 0, 0);
        __syncthreads();
    }

    // -------- epilogue: C/D layout col=lane&15, row=(lane>>4)*4+r  (m89/m91)
    const int rbase = m0 + wr * 64 + (lane >> 4) * 4;
    const int cbase = n0 + wc * 64;
    #pragma unroll
    for (int n = 0; n < 4; ++n) {
        const int col = cbase + n * 16 + lrow;
        const float bv = bias2[col];
        #pragma unroll
        for (int m = 0; m < 4; ++m) {
            const int row0 = rbase + m * 16;
            #pragma unroll
            for (int r = 0; r < 4; ++r) {
                C[(size_t)(row0 + r) * H_DIM + col] = acc[m][n][r] + bv;
            }
        }
    }
}

// ---------------- launcher ----------------
extern "C" void kernel_launch(void* const* d_in, const int* in_sizes, int n_in,
                              void* d_out, int out_size, void* d_ws, size_t ws_size,
                              hipStream_t stream) {
    const float* a      = (const float*)d_in[0];
    const float* v      = (const float*)d_in[1];
    const float* l      = (const float*)d_in[2];
    const float* qmask  = (const float*)d_in[3];
    // d_in[4] umask: unused by reference
    const float* mu_a   = (const float*)d_in[5];
    const float* mu_v   = (const float*)d_in[6];
    const float* mu_l   = (const float*)d_in[7];
    const float* shifta = (const float*)d_in[8];
    const float* shiftv = (const float*)d_in[9];
    const float* turna  = (const float*)d_in[10];
    const float* turnb  = (const float*)d_in[11];
    const float* W1     = (const float*)d_in[12];
    const float* b1     = (const float*)d_in[13];
    const float* W2     = (const float*)d_in[14];
    // d_in[15] b2: cancels in xr+xi
    float* out = (float*)d_out;

    char* ws = (char*)d_ws;
    unsigned short* Afeat = (unsigned short*)ws;                       // M*K_CAT bf16
    size_t offB  = (size_t)M_DIM * K_CAT * sizeof(unsigned short);     // 57.7 MB
    unsigned short* Bt = (unsigned short*)(ws + offB);                 // H*K_CAT bf16
    size_t offBias = offB + (size_t)H_DIM * K_CAT * sizeof(unsigned short);
    float* bias2 = (float*)(ws + offBias);
    size_t offTT = offBias + 4096;
    float4* TT = (float4*)(ws + offTT);                                // T*D float4

    prep_all_kernel<<<(H_DIM * K_CAT + 255) / 256, 256, 0, stream>>>(
        W1, b1, W2, turna, turnb, Bt, bias2, TT);
    feat_scan_kernel<<<B_DIM * 2, 256, 0, stream>>>(
        a, v, l, qmask, mu_a, mu_v, mu_l, shifta, shiftv, TT, (unsigned int*)Afeat);
    dim3 grid(H_DIM / BN, M_DIM / BM);     // x = N-tiles (4, fast), y = M-tiles
    gemm_kernel<<<grid, 256, 0, stream>>>(Afeat, Bt, bias2, out);
}